// Round 3
// baseline (58.212 us; speedup 1.0000x reference)
//
#include <hip/hip_runtime.h>
#include <hip/hip_bf16.h>

// FTRL wide-model forward. Reference:
//   z_g = z[idx]; n_g = n[idx]
//   w = (|z_g| <= L1) ? 0 : (sign(z_g)*L1 - z_g) / ((BETA + sqrt(n_g))/ALPHA + L2)
//   out = sigmoid(clip(sum_f w, -35, 35) + fc_b)
// Hyperparams baked in: ALPHA=0.1, BETA=1.0, L1=1.0, L2=1.0
//   -> denominator = 10*sqrt(n) + 11
//
// B=16384, F=100, D=2^26. One 64-lane wave per sample.
// MLP structure: both idx loads, then both z gathers, then both conditional
// n gathers issued before any dependent use (3 latency stages).
// Round 3: PLAIN loads (no nontemporal) — per-replay working set (~170 MB of
// distinct lines) fits the 256 MB Infinity Cache, and graph replays reuse the
// same indices, so let L2/L3 retain the gathered lines across replays.

__global__ __launch_bounds__(256) void ftrl_wide_kernel(
    const int* __restrict__ idx,     // (B, F)
    const float* __restrict__ z,     // (D,)
    const float* __restrict__ n,     // (D,)
    const float* __restrict__ fc_b,  // (1,)
    float* __restrict__ out,         // (B,)
    int B, int F) {
  const int gtid = blockIdx.x * blockDim.x + threadIdx.x;
  const int wave = gtid >> 6;   // one wave per sample
  const int lane = threadIdx.x & 63;
  if (wave >= B) return;

  const int* __restrict__ row = idx + (long long)wave * F;
  const bool has2 = (lane + 64) < F;   // F=100: lanes 0..35 take a 2nd feature

  // Stage 1: both index loads in flight together (coalesced).
  const int j0 = row[lane];
  int j1 = 0;
  if (has2) j1 = row[lane + 64];

  // Stage 2: both z gathers in flight together (cacheable).
  const float zg0 = z[j0];
  float zg1 = 0.0f;
  if (has2) zg1 = z[j1];

  // Stage 3: both conditional n gathers in flight together.
  const bool need0 = fabsf(zg0) > 1.0f;           // w != 0 iff |z| > L1
  const bool need1 = has2 && (fabsf(zg1) > 1.0f);
  float ng0 = 0.0f, ng1 = 0.0f;
  if (need0) ng0 = n[j0];
  if (need1) ng1 = n[j1];

  // Arithmetic.
  float acc = 0.0f;
  if (need0) {
    const float sgn = (zg0 < 0.0f) ? -1.0f : 1.0f;
    acc += (sgn - zg0) / fmaf(10.0f, sqrtf(ng0), 11.0f);
  }
  if (need1) {
    const float sgn = (zg1 < 0.0f) ? -1.0f : 1.0f;
    acc += (sgn - zg1) / fmaf(10.0f, sqrtf(ng1), 11.0f);
  }

  // 64-lane butterfly reduction
  #pragma unroll
  for (int off = 32; off > 0; off >>= 1) acc += __shfl_down(acc, off);

  if (lane == 0) {
    const float wz = fminf(fmaxf(acc, -35.0f), 35.0f);
    const float x = wz + fc_b[0];        // deep_z is just the bias
    out[wave] = 1.0f / (1.0f + __expf(-x));
  }
}

extern "C" void kernel_launch(void* const* d_in, const int* in_sizes, int n_in,
                              void* d_out, int out_size, void* d_ws, size_t ws_size,
                              hipStream_t stream) {
  // setup_inputs order: X_w_indices (B*F int32), z (D f32), n (D f32),
  //                     fc_w (1 f32, unused: multiplies zeros), fc_b (1 f32)
  const int* idx    = (const int*)d_in[0];
  const float* z    = (const float*)d_in[1];
  const float* n    = (const float*)d_in[2];
  const float* fc_b = (const float*)d_in[4];
  float* out        = (float*)d_out;

  const int B = out_size;               // 16384
  const int F = in_sizes[0] / B;        // 100

  const int threads = 256;              // 4 waves/block -> 4 samples/block
  const int blocks = (B * 64 + threads - 1) / threads;
  ftrl_wide_kernel<<<blocks, threads, 0, stream>>>(idx, z, n, fc_b, out, B, F);
}

// Round 4
// 55.768 us; speedup vs baseline: 1.0438x; 1.0438x over previous
//
#include <hip/hip_runtime.h>
#include <hip/hip_bf16.h>

// FTRL wide-model forward. Reference:
//   z_g = z[idx]; n_g = n[idx]
//   w = (|z_g| <= L1) ? 0 : (sign(z_g)*L1 - z_g) / ((BETA + sqrt(n_g))/ALPHA + L2)
//   out = sigmoid(clip(sum_f w, -35, 35) + fc_b)
// Hyperparams baked in: ALPHA=0.1, BETA=1.0, L1=1.0, L2=1.0
//   -> denominator = 10*sqrt(n) + 11
//
// B=16384, F=100, D=2^26. One 64-lane wave per sample.
// Config (measured best): non-temporal z/n gathers (56.5us vs 58.2 plain),
// full MLP staging (idx -> z pair -> conditional n pair), int2-paired index
// load (lane l handles features 2l, 2l+1; lanes 0..49 active).

__global__ __launch_bounds__(256) void ftrl_wide_kernel(
    const int* __restrict__ idx,     // (B, F)
    const float* __restrict__ z,     // (D,)
    const float* __restrict__ n,     // (D,)
    const float* __restrict__ fc_b,  // (1,)
    float* __restrict__ out,         // (B,)
    int B, int F) {
  const int gtid = blockIdx.x * blockDim.x + threadIdx.x;
  const int wave = gtid >> 6;   // one wave per sample
  const int lane = threadIdx.x & 63;
  if (wave >= B) return;

  const int* __restrict__ row = idx + (long long)wave * F;
  const int half = F >> 1;                  // 50
  const bool active = lane < half;          // lanes 0..49 carry 2 features each

  // Stage 1: one coalesced int2 load covers both of this lane's features.
  int j0 = 0, j1 = 0;
  if (active) {
    const int2 jj = *reinterpret_cast<const int2*>(row + 2 * lane);
    j0 = jj.x; j1 = jj.y;
  }

  // Stage 2: both z gathers in flight together (non-temporal: measured best).
  float zg0 = 0.0f, zg1 = 0.0f;
  if (active) {
    zg0 = __builtin_nontemporal_load(z + j0);
    zg1 = __builtin_nontemporal_load(z + j1);
  }

  // Stage 3: both conditional n gathers in flight together.
  const bool need0 = fabsf(zg0) > 1.0f;     // w != 0 iff |z| > L1
  const bool need1 = fabsf(zg1) > 1.0f;     // (inactive lanes have zg==0)
  float ng0 = 0.0f, ng1 = 0.0f;
  if (need0) ng0 = __builtin_nontemporal_load(n + j0);
  if (need1) ng1 = __builtin_nontemporal_load(n + j1);

  // Arithmetic.
  float acc = 0.0f;
  if (need0) {
    const float sgn = (zg0 < 0.0f) ? -1.0f : 1.0f;
    acc += (sgn - zg0) / fmaf(10.0f, sqrtf(ng0), 11.0f);
  }
  if (need1) {
    const float sgn = (zg1 < 0.0f) ? -1.0f : 1.0f;
    acc += (sgn - zg1) / fmaf(10.0f, sqrtf(ng1), 11.0f);
  }

  // 64-lane butterfly reduction
  #pragma unroll
  for (int off = 32; off > 0; off >>= 1) acc += __shfl_down(acc, off);

  if (lane == 0) {
    const float wz = fminf(fmaxf(acc, -35.0f), 35.0f);
    const float x = wz + fc_b[0];        // deep_z is just the bias
    out[wave] = 1.0f / (1.0f + __expf(-x));
  }
}

extern "C" void kernel_launch(void* const* d_in, const int* in_sizes, int n_in,
                              void* d_out, int out_size, void* d_ws, size_t ws_size,
                              hipStream_t stream) {
  // setup_inputs order: X_w_indices (B*F int32), z (D f32), n (D f32),
  //                     fc_w (1 f32, unused: multiplies zeros), fc_b (1 f32)
  const int* idx    = (const int*)d_in[0];
  const float* z    = (const float*)d_in[1];
  const float* n    = (const float*)d_in[2];
  const float* fc_b = (const float*)d_in[4];
  float* out        = (float*)d_out;

  const int B = out_size;               // 16384
  const int F = in_sizes[0] / B;        // 100

  const int threads = 256;              // 4 waves/block -> 4 samples/block
  const int blocks = (B * 64 + threads - 1) / threads;
  ftrl_wide_kernel<<<blocks, threads, 0, stream>>>(idx, z, n, fc_b, out, B, F);
}